// Round 7
// baseline (290.318 us; speedup 1.0000x reference)
//
#include <hip/hip_runtime.h>
#include <cstdint>

#pragma clang fp contract(off)

#define BB 64
#define PP 32768
#define OO 50
#define THRESH_F 0.5f
#define VAR0 0.1f
#define VAR1 0.2f
#define NEGPOS_I 3
#define SS 32                    // k_loss splits per batch (1024 priors/block)
#define T1 16                    // priors per thread in k_match
#define NBLK (PP / (256 * T1))   // 8 k_match blocks per batch
#define NBH 4096                 // hist bins: float bits 30:19
#define SCAP 4096                // survivor capacity in k_resolve LDS

typedef unsigned long long u64;

// ---- K1: fused matcher. Row-best per prior in regs (rcp-based value, the
// round-5 shape: per-element v is independent work, no loop-carried mul
// chain). Column-best per truth: wave shfl-reduce of packed
// (iou_bits<<32)|(PP-p), deferred to LDS, block-reduced to bpm[b][blk][t]
// (plain writes — no atomics, no zero-init needed).
__global__ void __launch_bounds__(256)
k_match(const float* __restrict__ priors, const float* __restrict__ targets,
        float* __restrict__ bto, int* __restrict__ bti, u64* __restrict__ bpm) {
    __shared__ float tr4[OO * 4];
    __shared__ float trA[OO];
    __shared__ u64 wbest[4][OO];
    int b = blockIdx.y, blk = blockIdx.x, tid = threadIdx.x;
    int lane = tid & 63, wv = tid >> 6;
    for (int i = tid; i < OO * 4; i += 256)
        tr4[i] = targets[(size_t)(b * OO + (i >> 2)) * 5 + (i & 3)];
    __syncthreads();
    if (tid < OO)
        trA[tid] = (tr4[tid*4+2] - tr4[tid*4]) * (tr4[tid*4+3] - tr4[tid*4+1]);
    __syncthreads();

    int p0 = blk * (256 * T1) + tid * T1;
    float bx0[T1], by0[T1], bx1[T1], by1[T1], aB[T1];
#pragma unroll
    for (int j = 0; j < T1; ++j) {
        float4 pr = ((const float4*)priors)[p0 + j];
        bx0[j] = pr.x - pr.z * 0.5f; by0[j] = pr.y - pr.w * 0.5f;
        bx1[j] = pr.x + pr.z * 0.5f; by1[j] = pr.y + pr.w * 0.5f;
        aB[j] = (bx1[j] - bx0[j]) * (by1[j] - by0[j]);
    }
    float rbv[T1]; int rbi[T1];
#pragma unroll
    for (int j = 0; j < T1; ++j) { rbv[j] = -1.0f; rbi[j] = 0; }

    for (int t = 0; t < OO; ++t) {
        float t0 = tr4[t*4], t1v = tr4[t*4+1], t2 = tr4[t*4+2], t3 = tr4[t*4+3];
        float aA = trA[t];
        float cbv = -1.0f; int cbp = p0;
#pragma unroll
        for (int j = 0; j < T1; ++j) {
            float ltx = fmaxf(t0, bx0[j]), lty = fmaxf(t1v, by0[j]);
            float rbx = fminf(t2, bx1[j]), rby = fminf(t3, by1[j]);
            float wx = fmaxf(rbx - ltx, 0.f), wy = fmaxf(rby - lty, 0.f);
            float inter = wx * wy;
            float uni = (aA + aB[j]) - inter;
            float v = inter * __builtin_amdgcn_rcpf(uni);
            if (v > rbv[j]) { rbv[j] = v; rbi[j] = t; }   // row: first-max
            if (v > cbv) { cbv = v; cbp = p0 + j; }       // col: smallest p
        }
        u64 pk = ((u64)__float_as_uint(cbv) << 32) | (unsigned)(PP - cbp);
        for (int s = 32; s >= 1; s >>= 1) {
            u64 o = __shfl_xor(pk, s, 64);
            if (o > pk) pk = o;
        }
        if (lane == 0) wbest[wv][t] = pk;
    }
    __syncthreads();
    if (tid < OO) {
        u64 m = wbest[0][tid];
        if (wbest[1][tid] > m) m = wbest[1][tid];
        if (wbest[2][tid] > m) m = wbest[2][tid];
        if (wbest[3][tid] > m) m = wbest[3][tid];
        bpm[(size_t)(b * NBLK + blk) * OO + tid] = m;
    }
    size_t bp = (size_t)b * PP + p0;
#pragma unroll
    for (int q = 0; q < T1 / 4; ++q) {
        ((float4*)bto)[(bp >> 2) + q] = make_float4(rbv[q*4], rbv[q*4+1], rbv[q*4+2], rbv[q*4+3]);
        ((int4*)bti)[(bp >> 2) + q]   = make_int4(rbi[q*4], rbi[q*4+1], rbi[q*4+2], rbi[q*4+3]);
    }
}

// ---- K2: conf/encode/smooth-L1/lc with forced-match applied via an LDS map
// (no global scatter kernel). Per block: reduce the NBLK column candidates
// per truth, map forced priors in-range to their truth idx (atomicMax ==
// last-write-wins of the sequential reference scatter). ----
__global__ void __launch_bounds__(256)
k_loss(const float* __restrict__ arm_loc, const float* __restrict__ arm_conf,
       const float* __restrict__ priors, const float* __restrict__ targets,
       const float* __restrict__ bto, const int* __restrict__ bti,
       const u64* __restrict__ bpm,
       float* __restrict__ lcm, float* __restrict__ pll,
       float* __restrict__ pplc, int* __restrict__ pnp) {
    __shared__ int fmap[1024];
    __shared__ float s1[256], s2[256]; __shared__ int s3[256];
    int b = blockIdx.y, s = blockIdx.x, tid = threadIdx.x;
    int pbase = s * 1024;

    for (int i = tid; i < 1024; i += 256) fmap[i] = -1;
    __syncthreads();
    if (tid < OO) {
        u64 m = 0;
#pragma unroll
        for (int k2 = 0; k2 < NBLK; ++k2) {
            u64 v = bpm[(size_t)(b * NBLK + k2) * OO + tid];
            if (v > m) m = v;
        }
        int p = PP - (int)(unsigned)(m & 0xFFFFFFFFull);
        if (p >= pbase && p < pbase + 1024) atomicMax(&fmap[p - pbase], tid);
    }
    __syncthreads();

    int p = pbase + tid * 4;
    size_t bp = (size_t)b * PP + p;
    float4 ov4 = ((const float4*)bto)[bp >> 2];
    int4   ti4 = ((const int4*)bti)[bp >> 2];
    float4 ca  = ((const float4*)arm_conf)[bp >> 1];
    float4 cb  = ((const float4*)arm_conf)[(bp >> 1) + 1];
    float ovs[4] = {ov4.x, ov4.y, ov4.z, ov4.w};
    int   tis[4] = {ti4.x, ti4.y, ti4.z, ti4.w};
    float cs[8]  = {ca.x, ca.y, ca.z, ca.w, cb.x, cb.y, cb.z, cb.w};

    float ll = 0.0f, plc = 0.0f; int np = 0;
    float outv[4];
    for (int c = 0; c < 4; ++c) {
        int f = fmap[tid * 4 + c];
        int ti = (f >= 0) ? f : tis[c];
        bool thr = (f >= 0) || !(ovs[c] < THRESH_F);
        const float* tb = &targets[(size_t)(b * OO + ti) * 5];
        int label = (tb[4] >= 0.0f) ? 1 : 0;
        int conf = thr ? label : 0;
        float c0 = cs[c * 2], c1 = cs[c * 2 + 1];
        float m = fmaxf(c0, c1);
        // identical to log(exp(c0-m)+exp(c1-m))+m: the max term is expf(0)==1
        float lse = __logf(1.0f + __expf(-fabsf(c0 - c1))) + m;
        float picked = (conf == 1) ? c1 : c0;
        float lc = lse - picked;
        bool pos = conf > 0;
        outv[c] = pos ? 0.0f : lc;
        if (pos) {
            np++; plc += lc;
            float4 pr = ((const float4*)priors)[p + c];
            float gx = ((tb[0] + tb[2]) * 0.5f - pr.x) / (VAR0 * pr.z);
            float gy = ((tb[1] + tb[3]) * 0.5f - pr.y) / (VAR0 * pr.w);
            float gw = __logf((tb[2] - tb[0]) / pr.z) / VAR1;
            float gh = __logf((tb[3] - tb[1]) / pr.w) / VAR1;
            float g[4] = {gx, gy, gw, gh};
            float4 ld = ((const float4*)arm_loc)[bp + c];
            float lds_[4] = {ld.x, ld.y, ld.z, ld.w};
            for (int q = 0; q < 4; ++q) {
                float d = lds_[q] - g[q];
                float ad = fabsf(d);
                ll += (ad < 1.0f) ? 0.5f * d * d : ad - 0.5f;
            }
        }
    }
    ((float4*)lcm)[bp >> 2] = make_float4(outv[0], outv[1], outv[2], outv[3]);

    s1[tid] = ll; s2[tid] = plc; s3[tid] = np;
    __syncthreads();
    for (int st = 128; st > 0; st >>= 1) {
        if (tid < st) { s1[tid] += s1[tid+st]; s2[tid] += s2[tid+st]; s3[tid] += s3[tid+st]; }
        __syncthreads();
    }
    if (tid == 0) {
        pll[s * BB + b] = s1[0];
        pplc[s * BB + b] = s2[0];
        pnp[s * BB + b] = s3[0];
    }
}

// Shared-memory suffix-scan + k-th-largest bin selection over nb bins.
__device__ __forceinline__ void suffix_select(
    int nb, int* hc, float* hs, int* sc, float* sf,
    int* s_chunk, int* s_r, float* s_S, unsigned* s_bin, int tid) {
    int per = nb >> 8;
    int c = 0; float f = 0.f;
    int base = tid * per;
    for (int i = 0; i < per; ++i) { c += hc[base + i]; f += hs[base + i]; }
    sc[tid] = c; sf[tid] = f;
    __syncthreads();
    for (int off = 1; off < 256; off <<= 1) {
        int cv = (tid + off < 256) ? sc[tid + off] : 0;
        float fv = (tid + off < 256) ? sf[tid + off] : 0.f;
        __syncthreads();
        sc[tid] += cv; sf[tid] += fv;
        __syncthreads();
    }
    int r = *s_r;
    int nxt = (tid == 255) ? 0 : sc[tid + 1];
    if (sc[tid] >= r && nxt < r) *s_chunk = tid;
    __syncthreads();
    if (tid == 0) {
        int ch = *s_chunk;
        int r2 = r - ((ch == 255) ? 0 : sc[ch + 1]);
        float S2 = *s_S + ((ch == 255) ? 0.f : sf[ch + 1]);
        int binSel = ch * per;
        for (int i = per - 1; i >= 0; --i) {
            int bin = ch * per + i;
            int cb = hc[bin];
            if (r2 <= cb) { binSel = bin; break; }
            r2 -= cb; S2 += hs[bin];
        }
        *s_bin = (unsigned)binSel; *s_r = r2; *s_S = S2;
    }
    __syncthreads();
}

// ---- K3: per-batch top-k sum. One block per batch: builds the 12-bit
// count+sum hist from the L2-resident 128 KB slice (2-copy LDS hist),
// selects, compacts survivors to LDS, two tiny LDS radix passes. ----
__global__ void __launch_bounds__(256)
k_resolve(const float* __restrict__ lcm, const int* __restrict__ pnp,
          float* __restrict__ topk) {
    __shared__ int hc2[2][NBH]; __shared__ float hs2[2][NBH];
    __shared__ float sbuf[SCAP];
    __shared__ int sc[256]; __shared__ float sf[256];
    __shared__ int s_chunk, s_r, s_cnt; __shared__ float s_S; __shared__ unsigned s_bin;
    int b = blockIdx.x, tid = threadIdx.x;
    int cp = (tid >> 7) & 1, lane = tid & 63;
    int* hc = hc2[0]; float* hsv = hs2[0];

    for (int i = tid; i < NBH; i += 256) {
        hc2[0][i] = 0; hc2[1][i] = 0; hs2[0][i] = 0.f; hs2[1][i] = 0.f;
    }
    if (tid == 0) s_cnt = 0;
    __syncthreads();

    const float4* v4 = (const float4*)(lcm + (size_t)b * PP);
    for (int i = tid; i < PP / 4; i += 256) {
        float4 x = v4[i];
        float xs[4] = {x.x, x.y, x.z, x.w};
        for (int c = 0; c < 4; ++c) {
            unsigned bin = __float_as_uint(xs[c]) >> 19;   // < NBH (finite >= 0)
            atomicAdd(&hc2[cp][bin], 1);
            atomicAdd(&hs2[cp][bin], xs[c]);
        }
    }
    __syncthreads();
    for (int i = tid; i < NBH; i += 256) {        // merge copies (own bins)
        hc2[0][i] += hc2[1][i]; hs2[0][i] += hs2[1][i];
    }
    int np = 0;
    for (int i = 0; i < SS; ++i) np += pnp[i * BB + b];
    int k = NEGPOS_I * np; if (k > PP - 1) k = PP - 1;
    if (k <= 0) { if (tid == 0) topk[b] = 0.f; return; }
    if (tid == 0) { s_r = k; s_S = 0.f; }
    __syncthreads();
    suffix_select(NBH, hc, hsv, sc, sf, &s_chunk, &s_r, &s_S, &s_bin, tid);
    unsigned bin1 = s_bin;

    // compact survivors (top-12 bits == bin1) into LDS
    for (int i = tid; i < PP / 4; i += 256) {
        float4 x = v4[i];
        float xs[4] = {x.x, x.y, x.z, x.w};
        for (int c = 0; c < 4; ++c) {
            bool mt = (__float_as_uint(xs[c]) >> 19) == bin1;
            u64 bal = __ballot(mt);
            if (bal) {
                int leader = __ffsll((long long)bal) - 1;
                int cnt = __popcll(bal);
                int posi = __popcll(bal & ((1ull << lane) - 1ull));
                int basei = 0;
                if (lane == leader) basei = atomicAdd(&s_cnt, cnt);
                basei = __shfl(basei, leader, 64);
                if (mt) { int idx = basei + posi; if (idx < SCAP) sbuf[idx] = xs[c]; }
            }
        }
    }
    __syncthreads();
    int n = s_cnt; bool useLds = (n <= SCAP);

    // pass A: bits 18:9 (1024 bins)
    for (int i = tid; i < 1024; i += 256) { hc[i] = 0; hsv[i] = 0.f; }
    __syncthreads();
    if (useLds) {
        for (int i = tid; i < n; i += 256) {
            float x = sbuf[i]; unsigned u = __float_as_uint(x);
            atomicAdd(&hc[(u >> 9) & 1023u], 1); atomicAdd(&hsv[(u >> 9) & 1023u], x);
        }
    } else {
        for (int i = tid; i < PP / 4; i += 256) {
            float4 x = v4[i]; float xs[4] = {x.x, x.y, x.z, x.w};
            for (int c = 0; c < 4; ++c) {
                unsigned u = __float_as_uint(xs[c]);
                if ((u >> 19) == bin1) {
                    atomicAdd(&hc[(u >> 9) & 1023u], 1);
                    atomicAdd(&hsv[(u >> 9) & 1023u], xs[c]);
                }
            }
        }
    }
    __syncthreads();
    suffix_select(1024, hc, hsv, sc, sf, &s_chunk, &s_r, &s_S, &s_bin, tid);
    unsigned bin2 = s_bin;
    unsigned pre2 = (bin1 << 10) | bin2;

    // pass B: bits 8:0 (512 bins)
    for (int i = tid; i < 512; i += 256) { hc[i] = 0; hsv[i] = 0.f; }
    __syncthreads();
    if (useLds) {
        for (int i = tid; i < n; i += 256) {
            float x = sbuf[i]; unsigned u = __float_as_uint(x);
            if (((u >> 9) & 1023u) == bin2) { atomicAdd(&hc[u & 511u], 1); atomicAdd(&hsv[u & 511u], x); }
        }
    } else {
        for (int i = tid; i < PP / 4; i += 256) {
            float4 x = v4[i]; float xs[4] = {x.x, x.y, x.z, x.w};
            for (int c = 0; c < 4; ++c) {
                unsigned u = __float_as_uint(xs[c]);
                if ((u >> 9) == pre2) { atomicAdd(&hc[u & 511u], 1); atomicAdd(&hsv[u & 511u], xs[c]); }
            }
        }
    }
    __syncthreads();
    suffix_select(512, hc, hsv, sc, sf, &s_chunk, &s_r, &s_S, &s_bin, tid);
    if (tid == 0) {
        unsigned tb = (pre2 << 9) | s_bin;
        topk[b] = s_S + (float)s_r * __uint_as_float(tb);
    }
}

// ---- K4: final reduction across batches -> (loss_l/N, loss_c/N) ----
__global__ void k_final(const float* __restrict__ pll, const float* __restrict__ pplc,
                        const int* __restrict__ pnp, const float* __restrict__ topk,
                        float* __restrict__ out) {
    int b = threadIdx.x;          // 64 threads = one wave, one batch each
    float ll = 0.f, plc = 0.f; int np = 0;
    for (int s = 0; s < SS; ++s) {
        ll += pll[s * BB + b];
        plc += pplc[s * BB + b];
        np += pnp[s * BB + b];
    }
    float cc = plc + topk[b];
    for (int s = 32; s > 0; s >>= 1) {
        ll += __shfl_down(ll, s);
        cc += __shfl_down(cc, s);
        np += __shfl_down(np, s);
    }
    if (b == 0) {
        float N = (float)np;
        out[0] = ll / N;
        out[1] = cc / N;
    }
}

extern "C" void kernel_launch(void* const* d_in, const int* in_sizes, int n_in,
                              void* d_out, int out_size, void* d_ws, size_t ws_size,
                              hipStream_t stream) {
    const float* arm_loc  = (const float*)d_in[0];
    const float* arm_conf = (const float*)d_in[1];
    const float* priors   = (const float*)d_in[4];
    const float* targets  = (const float*)d_in[5];
    float* out = (float*)d_out;

    char* w = (char*)d_ws;
    float* bto = (float*)w;  w += sizeof(float) * (size_t)BB * PP;    // 8 MB
    int*   bti = (int*)w;    w += sizeof(int)   * (size_t)BB * PP;    // 8 MB
    float* lcm = (float*)w;  w += sizeof(float) * (size_t)BB * PP;    // 8 MB
    u64*   bpm = (u64*)w;    w += sizeof(u64)   * BB * NBLK * OO;     // 200 KB
    float* pll  = (float*)w; w += sizeof(float) * BB * SS;
    float* pplc = (float*)w; w += sizeof(float) * BB * SS;
    int*   pnp  = (int*)w;   w += sizeof(int)   * BB * SS;
    float* topk = (float*)w; w += sizeof(float) * BB;
    // every ws buffer is fully written before read each call — no zero-init.

    k_match<<<dim3(NBLK, BB), 256, 0, stream>>>(priors, targets, bto, bti, bpm);
    k_loss<<<dim3(SS, BB), 256, 0, stream>>>(arm_loc, arm_conf, priors, targets,
                                             bto, bti, bpm, lcm, pll, pplc, pnp);
    k_resolve<<<BB, 256, 0, stream>>>(lcm, pnp, topk);
    k_final<<<1, 64, 0, stream>>>(pll, pplc, pnp, topk, out);
}